// Round 1
// baseline (575.206 us; speedup 1.0000x reference)
//
#include <hip/hip_runtime.h>
#include <math.h>

#define NB 32
#define NN 4096      // 64*64
#define NNN 262144   // 64^3
#define PERMI(i) ((((i)&7)<<3)|((i)>>3))

__device__ __forceinline__ float2 cadd(float2 a, float2 b){ return make_float2(a.x+b.x, a.y+b.y); }
__device__ __forceinline__ float2 csub(float2 a, float2 b){ return make_float2(a.x-b.x, a.y-b.y); }
__device__ __forceinline__ float2 cmulc(float2 a, float2 b){ return make_float2(a.x*b.x - a.y*b.y, a.x*b.y + a.y*b.x); }
template<int S> __device__ __forceinline__ float2 cmuli(float2 a){
  return (S>0)? make_float2(-a.y,a.x) : make_float2(a.y,-a.x);
}

// 8-point DFT, natural order in/out. S=-1 forward, S=+1 inverse (unnormalized).
template<int S>
__device__ __forceinline__ void dft8(float2* a){
  const float r_ = 0.70710678118654752f;
  float2 t0=cadd(a[0],a[4]), t1=csub(a[0],a[4]);
  float2 t2=cadd(a[2],a[6]), t3=csub(a[2],a[6]);
  float2 u0=cadd(a[1],a[5]), u1=csub(a[1],a[5]);
  float2 u2=cadd(a[3],a[7]), u3=csub(a[3],a[7]);
  float2 E0=cadd(t0,t2), E2=csub(t0,t2);
  float2 it3=cmuli<S>(t3);
  float2 E1=cadd(t1,it3), E3=csub(t1,it3);
  float2 O0=cadd(u0,u2), O2=csub(u0,u2);
  float2 iu3=cmuli<S>(u3);
  float2 O1=cadd(u1,iu3), O3=csub(u1,iu3);
  const float sr = (S>0)? r_ : -r_;
  float2 W1 = make_float2(r_, sr);
  float2 W3 = make_float2(-r_, sr);
  float2 o1 = cmulc(O1,W1);
  float2 o2 = cmuli<S>(O2);
  float2 o3 = cmulc(O3,W3);
  a[0]=cadd(E0,O0); a[4]=csub(E0,O0);
  a[1]=cadd(E1,o1); a[5]=csub(E1,o1);
  a[2]=cadd(E2,o2); a[6]=csub(E2,o2);
  a[3]=cadd(E3,o3); a[7]=csub(E3,o3);
}

// 64-point DFT (radix-8 x 8). Input: vin natural order (PIN=false) or
// "PERM-placed" order (PIN=true, i.e. logical i lives at vin[PERMI(i)]).
// Output: logical index i lives at v[PERMI(i)].
// In-place (vin==v) is safe only for PIN=false.
template<int S, bool PIN>
__device__ __forceinline__ void fft64(float2* vin, float2* v){
  #pragma unroll
  for(int n2=0;n2<8;n2++){
    float2 t[8];
    #pragma unroll
    for(int n1=0;n1<8;n1++) t[n1] = vin[PIN ? (8*n2+n1) : (8*n1+n2)];
    dft8<S>(t);
    #pragma unroll
    for(int k1=0;k1<8;k1++) v[8*k1+n2] = t[k1];
  }
  const float TWC[8]={1.f,0.9951847266721969f,0.9807852804032304f,0.9569403357322088f,
                      0.9238795325112867f,0.8819212643483551f,0.8314696123025452f,0.7730104533627370f};
  const float TWS[8]={0.f,0.0980171403295606f,0.1950903220161283f,0.2902846772544624f,
                      0.3826834323650898f,0.4713967368259976f,0.5555702330196022f,0.6343932841636455f};
  #pragma unroll
  for(int k1=1;k1<8;k1++){
    float2 wb = make_float2(TWC[k1], (S>0)? TWS[k1] : -TWS[k1]);
    float2 w = wb;
    #pragma unroll
    for(int n2=1;n2<8;n2++){
      v[8*k1+n2] = cmulc(v[8*k1+n2], w);
      w = cmulc(w, wb);
    }
  }
  #pragma unroll
  for(int k1=0;k1<8;k1++){
    float2 t[8];
    #pragma unroll
    for(int n2=0;n2<8;n2++) t[n2]=v[8*k1+n2];
    dft8<S>(t);
    #pragma unroll
    for(int k2=0;k2<8;k2++) v[8*k1+k2]=t[k2];
  }
}

// ---------------- affine params ----------------
// aff[b*16 + 0..8] = rm (row-major), [9..11] = c for the X warp (masks use c=0)
__global__ void k_affine(const float* __restrict__ theta, float* __restrict__ aff){
  int b = threadIdx.x;
  if(b >= NB) return;
  const float* t = theta + b*6;
  const float PIf = 3.14159265358979323846f;
  float phi = t[0]*(2.f*PIf) - PIf;
  float th  = t[1]*(2.f*PIf) - PIf;
  float psi = t[2]*(2.f*PIf) - PIf;
  float cph = cosf(phi), sph = sinf(phi);
  float cth = cosf(th),  sth = sinf(th);
  float cps = cosf(psi), sps = sinf(psi);
  // R = Rz(phi) @ Ry(th) @ Rz(psi)
  float R00 = cph*cth*cps - sph*sps;
  float R01 = -cph*cth*sps - sph*cps;
  float R02 = cph*sth;
  float R10 = sph*cth*cps + cph*sps;
  float R11 = -sph*cth*sps + cph*cps;
  float R12 = sph*sth;
  float R20 = -sth*cps;
  float R21 = sth*sps;
  float R22 = cth;
  // rm = R^T
  float rm0=R00, rm1=R10, rm2=R20;
  float rm3=R01, rm4=R11, rm5=R21;
  float rm6=R02, rm7=R12, rm8=R22;
  float* o = aff + b*16;
  o[0]=rm0; o[1]=rm1; o[2]=rm2;
  o[3]=rm3; o[4]=rm4; o[5]=rm5;
  o[6]=rm6; o[7]=rm7; o[8]=rm8;
  const float sc = 64.0f/66.0f;   // shape/(shape+2)
  float lx = (2.f*t[3]-1.f)*sc;
  float ly = (2.f*t[4]-1.f)*sc;
  float lz = (2.f*t[5]-1.f)*sc;
  o[9]  = -(rm0*lx + rm1*ly + rm2*lz);
  o[10] = -(rm3*lx + rm4*ly + rm5*lz);
  o[11] = -(rm6*lx + rm7*ly + rm8*lz);
}

// ---------------- mask warp (rotation only, 64-grid, clamp) ----------------
__global__ void k_warp_masks(const float* __restrict__ m1, const float* __restrict__ m2,
                             const float* __restrict__ aff,
                             float* __restrict__ M1, float* __restrict__ M2){
  int vid = blockIdx.x*blockDim.x + threadIdx.x;
  if (vid >= NB*NNN) return;
  int b = vid >> 18;
  int r = vid & (NNN-1);
  int x = r >> 12, y = (r >> 6) & 63, z = r & 63;
  const float* a = aff + b*16;
  float gx = x*(2.f/63.f) - 1.f;
  float gy = y*(2.f/63.f) - 1.f;
  float gz = z*(2.f/63.f) - 1.f;
  float tx = a[0]*gx + a[1]*gy + a[2]*gz;
  float ty = a[3]*gx + a[4]*gy + a[5]*gz;
  float tz = a[6]*gx + a[7]*gy + a[8]*gz;
  float px = (tx+1.f)*31.5f;
  float py = (ty+1.f)*31.5f;
  float pz = (tz+1.f)*31.5f;
  int xf = (int)floorf(px), yf = (int)floorf(py), zf = (int)floorf(pz);
  int x0 = min(max(xf,0),63),   x1 = min(max(xf+1,0),63);
  int y0 = min(max(yf,0),63),   y1 = min(max(yf+1,0),63);
  int z0 = min(max(zf,0),63),   z1 = min(max(zf+1,0),63);
  float dx = px - (float)x0, dy = py - (float)y0, dz = pz - (float)z0;
  float ex = 1.f-dx, ey = 1.f-dy, ez = 1.f-dz;
  float w000=ex*ey*ez, w001=ex*ey*dz, w010=ex*dy*ez, w011=ex*dy*dz;
  float w100=dx*ey*ez, w101=dx*ey*dz, w110=dx*dy*ez, w111=dx*dy*dz;
  const float* s1 = m1 + b*NNN;
  const float* s2 = m2 + b*NNN;
  int i000=(x0<<12)+(y0<<6)+z0, i001=(x0<<12)+(y0<<6)+z1;
  int i010=(x0<<12)+(y1<<6)+z0, i011=(x0<<12)+(y1<<6)+z1;
  int i100=(x1<<12)+(y0<<6)+z0, i101=(x1<<12)+(y0<<6)+z1;
  int i110=(x1<<12)+(y1<<6)+z0, i111=(x1<<12)+(y1<<6)+z1;
  float r1 = w000*s1[i000]+w001*s1[i001]+w010*s1[i010]+w011*s1[i011]
           + w100*s1[i100]+w101*s1[i101]+w110*s1[i110]+w111*s1[i111];
  float r2 = w000*s2[i000]+w001*s2[i001]+w010*s2[i010]+w011*s2[i011]
           + w100*s2[i100]+w101*s2[i101]+w110*s2[i110]+w111*s2[i111];
  M1[vid] = r1;
  M2[vid] = r2;
}

// ---------------- X warp (66-grid over conceptual zero-padded image) --------
__device__ __forceinline__ float fetch_pad(const float* __restrict__ s, int xi, int yi, int zi){
  // conceptual padded image: index in [0,66); interior [1,64] maps to X[idx-1], else 0
  if ((unsigned)(xi-1) < 64u && (unsigned)(yi-1) < 64u && (unsigned)(zi-1) < 64u)
    return s[((xi-1)<<12) + ((yi-1)<<6) + (zi-1)];
  return 0.f;
}

__global__ void k_warp_x(const float* __restrict__ X, const float* __restrict__ aff,
                         float* __restrict__ Xt){
  int vid = blockIdx.x*blockDim.x + threadIdx.x;
  if (vid >= NB*NNN) return;
  int b = vid >> 18;
  int r = vid & (NNN-1);
  int x = r >> 12, y = (r >> 6) & 63, z = r & 63;
  const float* a = aff + b*16;
  float gx = (float)(x+1)*(2.f/65.f) - 1.f;   // linspace(-1,1,66)[x+1]
  float gy = (float)(y+1)*(2.f/65.f) - 1.f;
  float gz = (float)(z+1)*(2.f/65.f) - 1.f;
  float tx = a[0]*gx + a[1]*gy + a[2]*gz + a[9];
  float ty = a[3]*gx + a[4]*gy + a[5]*gz + a[10];
  float tz = a[6]*gx + a[7]*gy + a[8]*gz + a[11];
  float px = (tx+1.f)*32.5f;   // (t+1)*(66-1)/2
  float py = (ty+1.f)*32.5f;
  float pz = (tz+1.f)*32.5f;
  int xf = (int)floorf(px), yf = (int)floorf(py), zf = (int)floorf(pz);
  int x0 = min(max(xf,0),65),   x1 = min(max(xf+1,0),65);
  int y0 = min(max(yf,0),65),   y1 = min(max(yf+1,0),65);
  int z0 = min(max(zf,0),65),   z1 = min(max(zf+1,0),65);
  float dx = px - (float)x0, dy = py - (float)y0, dz = pz - (float)z0;
  float ex = 1.f-dx, ey = 1.f-dy, ez = 1.f-dz;
  const float* s = X + b*NNN;
  float rv = ex*ey*ez*fetch_pad(s,x0,y0,z0)
           + ex*ey*dz*fetch_pad(s,x0,y0,z1)
           + ex*dy*ez*fetch_pad(s,x0,y1,z0)
           + ex*dy*dz*fetch_pad(s,x0,y1,z1)
           + dx*ey*ez*fetch_pad(s,x1,y0,z0)
           + dx*ey*dz*fetch_pad(s,x1,y0,z1)
           + dx*dy*ez*fetch_pad(s,x1,y1,z0)
           + dx*dy*dz*fetch_pad(s,x1,y1,z1);
  Xt[vid] = rv;
}

// ---------------- forward slab: FFT over y then z for one (b,x) slab --------
__global__ __launch_bounds__(64,1) void k_fwd_slab(const float* __restrict__ src, float2* __restrict__ dst){
  __shared__ float re[64*65];
  __shared__ float im[64*65];
  int s = blockIdx.x;          // b*64 + x
  int t = threadIdx.x;         // z-column for phase 1, ky-row for phase 2
  const float* p = src + (size_t)s*NN;
  float2 v[64];
  #pragma unroll
  for(int y=0;y<64;y++) v[y] = make_float2(p[y*64+t], 0.f);   // coalesced
  fft64<-1,false>(v, v);
  #pragma unroll
  for(int i=0;i<64;i++){ float2 q = v[PERMI(i)]; re[i*65+t]=q.x; im[i*65+t]=q.y; }
  __syncthreads();
  #pragma unroll
  for(int z=0;z<64;z++) v[z] = make_float2(re[t*65+z], im[t*65+z]);
  fft64<-1,false>(v, v);
  #pragma unroll
  for(int i=0;i<64;i++){ float2 q = v[PERMI(i)]; re[t*65+i]=q.x; im[t*65+i]=q.y; }
  __syncthreads();
  float2* d = dst + (size_t)s*NN;
  #pragma unroll
  for(int i=0;i<64;i++) d[i*64+t] = make_float2(re[i*65+t], im[i*65+t]);  // coalesced
}

// ------- conv along x: FFT-x, multiply by shifted mask, iFFT-x, in place ----
__global__ __launch_bounds__(256,1) void k_conv_x(float2* __restrict__ A, const float* __restrict__ M){
  int lid = blockIdx.x*blockDim.x + threadIdx.x;   // 32*64*64 lines
  int z = lid & 63, y = (lid>>6) & 63, b = lid>>12;
  float2* p = A + (size_t)b*NNN + y*64 + z;
  const float* m = M + (size_t)b*NNN + ((y^32)<<6) + (z^32);
  float2 v[64];
  #pragma unroll
  for(int k=0;k<64;k++) v[k] = p[(size_t)k*NN];
  fft64<-1,false>(v, v);
  // spectrum: logical kx=i at v[PERMI(i)]; multiply by mask[(kx^32),(ky^32),(kz^32)]
  #pragma unroll
  for(int i=0;i<64;i++){
    float mm = m[(size_t)(i^32)*NN];
    v[PERMI(i)].x *= mm;
    v[PERMI(i)].y *= mm;
  }
  float2 w[64];
  fft64<1,true>(v, w);
  #pragma unroll
  for(int i=0;i<64;i++) p[(size_t)i*NN] = w[PERMI(i)];
}

// -------- inverse slab: iFFT over y then z, scale, take real, write/acc -----
template<bool ACC>
__global__ __launch_bounds__(64,1) void k_inv_slab(const float2* __restrict__ src, float* __restrict__ dst){
  __shared__ float re[64*65];
  __shared__ float im[64*65];
  int s = blockIdx.x;
  int t = threadIdx.x;
  const float2* p = src + (size_t)s*NN;
  float2 v[64];
  #pragma unroll
  for(int ky=0;ky<64;ky++) v[ky] = p[ky*64+t];     // coalesced
  fft64<1,false>(v, v);
  #pragma unroll
  for(int i=0;i<64;i++){ float2 q = v[PERMI(i)]; re[i*65+t]=q.x; im[i*65+t]=q.y; }
  __syncthreads();
  #pragma unroll
  for(int kz=0;kz<64;kz++) v[kz] = make_float2(re[t*65+kz], im[t*65+kz]);
  fft64<1,false>(v, v);
  const float scl = 1.0f/262144.0f;   // 1/N^3 ifft normalization
  #pragma unroll
  for(int i=0;i<64;i++) re[t*65+i] = v[PERMI(i)].x * scl;
  __syncthreads();
  float* d = dst + (size_t)s*NN;
  #pragma unroll
  for(int i=0;i<64;i++){
    float val = re[i*65+t];
    if (ACC) d[i*64+t] += val; else d[i*64+t] = val;
  }
}

extern "C" void kernel_launch(void* const* d_in, const int* in_sizes, int n_in,
                              void* d_out, int out_size, void* d_ws, size_t ws_size,
                              hipStream_t stream){
  const float* X  = (const float*)d_in[0];
  const float* Y  = (const float*)d_in[1];
  const float* m1 = (const float*)d_in[2];
  const float* m2 = (const float*)d_in[3];
  const float* th = (const float*)d_in[4];
  float* out0 = (float*)d_out;              // output  [32,64,64,64,1]
  float* out1 = out0 + (size_t)NB*NNN;      // M1_t
  float* out2 = out1 + (size_t)NB*NNN;      // M2_t
  float2* A  = (float2*)d_ws;                                   // 64 MB complex work buffer
  float*  aff = (float*)((char*)d_ws + (size_t)NB*NNN*sizeof(float2));  // 32*16 floats

  k_affine<<<dim3(1), dim3(32), 0, stream>>>(th, aff);
  k_warp_masks<<<dim3(NB*NNN/256), dim3(256), 0, stream>>>(m1, m2, aff, out1, out2);
  k_warp_x<<<dim3(NB*NNN/256), dim3(256), 0, stream>>>(X, aff, out0);   // X_t staged in out0

  // X pipeline: fft(y,z) -> [fft-x * M1shift -> ifft-x] -> ifft(y,z) -> out0 (overwrite)
  k_fwd_slab<<<dim3(NB*64), dim3(64), 0, stream>>>(out0, A);
  k_conv_x<<<dim3(NB*NN/256), dim3(256), 0, stream>>>(A, out1);
  k_inv_slab<false><<<dim3(NB*64), dim3(64), 0, stream>>>(A, out0);

  // Y pipeline, accumulated
  k_fwd_slab<<<dim3(NB*64), dim3(64), 0, stream>>>(Y, A);
  k_conv_x<<<dim3(NB*NN/256), dim3(256), 0, stream>>>(A, out2);
  k_inv_slab<true><<<dim3(NB*64), dim3(64), 0, stream>>>(A, out0);
}